// Round 9
// baseline (586.546 us; speedup 1.0000x reference)
//
#include <hip/hip_runtime.h>

// x: [B=64, C=2048, J=8] fp32 ; W: [K=32, C=2048, I=16, J=8] fp32
// out v: [B=64, K=32, I=16] fp32
#define Bn 64
#define Cn 2048
#define Kn 32
#define In 16
#define EPSf 1e-7f

#define NOUT (Bn * Kn * In)   // 32768
#define KJ   (Cn * 8)         // 16384 contraction length
#define KSPL1 128             // iter-1 GEMM split-K (P1, 1024 blocks)
#define KSPL2 64              // iter-2 GEMM split-K (P4, 512 blocks)
#define GRID  1024

typedef short bf8v __attribute__((ext_vector_type(8)));
typedef float f4v  __attribute__((ext_vector_type(4)));
typedef float v2f  __attribute__((ext_vector_type(2)));

union U16B { uint4 u; bf8v v; unsigned short h[8]; };

__device__ __forceinline__ unsigned short f2bf(float f) {
    unsigned u = __float_as_uint(f);
    u += 0x7FFF + ((u >> 16) & 1);          // RNE
    return (unsigned short)(u >> 16);
}

__device__ __forceinline__ bf8v cvt8(float4 a, float4 b) {
    U16B o;
    o.h[0] = f2bf(a.x); o.h[1] = f2bf(a.y); o.h[2] = f2bf(a.z); o.h[3] = f2bf(a.w);
    o.h[4] = f2bf(b.x); o.h[5] = f2bf(b.y); o.h[6] = f2bf(b.z); o.h[7] = f2bf(b.w);
    return o.v;
}

__device__ __forceinline__ float dot8v(float4 wA, float4 wB, float4 xA, float4 xB) {
    union F2 { float4 f; v2f h[2]; };
    F2 ua{wA}, ub{wB}, xa{xA}, xb{xB};
    v2f s = ua.h[0] * xa.h[0];
    s += ua.h[1] * xa.h[1];
    s += ub.h[0] * xb.h[0];
    s += ub.h[1] * xb.h[1];
    return s.x + s.y;
}

// Device-wide barrier: counter+flag pair per barrier instance (zeroed by
// memsetAsync each call). RMW polls go to the device coherence point, so
// cross-XCD visibility is guaranteed; __threadfence() = agent-scope fence
// for the data written before the barrier.
__device__ __forceinline__ void gbar(unsigned* bar, int which) {
    __syncthreads();
    if (threadIdx.x == 0) {
        unsigned* cnt  = bar + 2 * which;
        unsigned* flag = bar + 2 * which + 1;
        __threadfence();
        if (atomicAdd(cnt, 1u) == GRID - 1u) {
            atomicExch(flag, 1u);
        } else {
            while (atomicAdd(flag, 0u) == 0u) __builtin_amdgcn_s_sleep(8);
        }
        __threadfence();
    }
    __syncthreads();
}

__global__ __launch_bounds__(256, 4) void kFused(
    const float* __restrict__ x, const float* __restrict__ W,
    float* __restrict__ out, unsigned* __restrict__ bar,
    float* __restrict__ bufA,   // P1: part1[128][32768] ; P3+: cc[32][2048][64]
    float* __restrict__ v1,     // 32768
    float* __restrict__ part2)  // 64 x 32768
{
    const int bid = blockIdx.x;
    const int tid = threadIdx.x;
    const int lane = tid & 63;

    __shared__ float e_s[4][8][33];
    __shared__ float dinv[32];

    // ================= P1: iter-1 GEMM partials (all 1024 blocks) ==========
    {
        const int nstrip = bid & 7;
        const int ksplit = bid >> 3;          // 0..127
        const int ks0    = ksplit * 4;
        const int m0     = (tid >> 6) * 16;

        f4v acc[4] = {};
        const float* xrow = x + (size_t)(m0 + (lane & 15)) * KJ + (lane >> 4) * 8;

        #pragma unroll
        for (int s = 0; s < 512 / KSPL1; ++s) {
            const int ks = ks0 + s;
            const float4* xp = (const float4*)(xrow + ks * 32);
            bf8v af = cvt8(xp[0], xp[1]);
            #pragma unroll
            for (int t = 0; t < 4; ++t) {
                const int nt = nstrip * 4 + t;            // == k_out
                const int c  = ks * 4 + (lane >> 4);
                const float4* wp = (const float4*)(W + (((size_t)nt * Cn + c) * 16 + (lane & 15)) * 8);
                bf8v bfr = cvt8(wp[0], wp[1]);
                acc[t] = __builtin_amdgcn_mfma_f32_16x16x32_bf16(af, bfr, acc[t], 0, 0, 0);
            }
        }
        float* pb = bufA + (size_t)ksplit * NOUT;
        const int col   = lane & 15;
        const int rbase = (lane >> 4) * 4;
        #pragma unroll
        for (int t = 0; t < 4; ++t) {
            const int n = (nstrip * 4 + t) * 16 + col;
            #pragma unroll
            for (int r = 0; r < 4; ++r)
                pb[(size_t)(m0 + rbase + r) * 512 + n] = acc[t][r];
        }
    }
    gbar(bar, 0);

    // ================= P2: v1 = squash(sum/32)  (blocks 0..127) ============
    if (bid < 128) {
        const int t = bid * 256 + tid;        // 0..32767
        float s = 0.0f;
        #pragma unroll 16
        for (int g = 0; g < KSPL1; ++g) s += bufA[(size_t)g * NOUT + t];
        s *= (1.0f / 32.0f);
        float sq = s * s;
        sq += __shfl_xor(sq, 1);
        sq += __shfl_xor(sq, 2);
        sq += __shfl_xor(sq, 4);
        sq += __shfl_xor(sq, 8);
        const float f = (sq / (1.0f + sq)) * rsqrtf(sq + EPSf);
        v1[t] = s * f;
    }
    gbar(bar, 1);

    // ================= P3: agreements + softmax -> cc (all blocks) =========
    // R7 kAgrCC body (53 us, best measured); 2 bg per block.
    {
        const int xcd = bid & 7;
        const int idx = bid >> 3;             // 0..127
        const int bgh = idx & 7;
        const int cgl = idx >> 3;             // 0..15
        const int cg  = xcd * 16 + cgl;       // 0..127
        const int k   = tid >> 3;
        const int ih  = tid & 7;
        float* cc = bufA;                     // part1 dead after P2

        for (int bgi = 0; bgi < 2; ++bgi) {
            const int bg = bgh * 2 + bgi;     // 0..15

            float v1r[4][2];
            #pragma unroll
            for (int b = 0; b < 4; ++b) {
                const float2 v = *(const float2*)(v1 + ((size_t)((bg * 4 + b) * Kn + k)) * In + 2 * ih);
                v1r[b][0] = v.x;
                v1r[b][1] = v.y;
            }

            for (int ch = 0; ch < 2; ++ch) {
                const int c0 = cg * 16 + ch * 8;

                #pragma unroll 2
                for (int cl = 0; cl < 8; ++cl) {
                    const int c = c0 + cl;
                    const float4* wp = (const float4*)(W + ((size_t)(k * Cn + c)) * 128 + ih * 16);
                    float4 w0 = wp[0], w1 = wp[1], w2 = wp[2], w3 = wp[3];
                    #pragma unroll
                    for (int b = 0; b < 4; ++b) {
                        const float4* xp = (const float4*)(x + ((size_t)((bg * 4 + b) * Cn + c)) * 8);
                        float4 x0 = xp[0], x1 = xp[1];
                        float a0 = dot8v(w0, w1, x0, x1);
                        float a1 = dot8v(w2, w3, x0, x1);
                        float p = a0 * v1r[b][0] + a1 * v1r[b][1];
                        p += __shfl_xor(p, 1);
                        p += __shfl_xor(p, 2);
                        p += __shfl_xor(p, 4);
                        if (ih == 0) e_s[b][cl][k] = __expf(p);
                    }
                }
                __syncthreads();

                {
                    const int p  = tid >> 3;   // 0..31
                    const int l  = tid & 7;
                    const int pb = p >> 3, pc = p & 7;
                    const float* ep = &e_s[pb][pc][4 * l];
                    float ssum = (ep[0] + ep[1]) + (ep[2] + ep[3]);
                    ssum += __shfl_xor(ssum, 1);
                    ssum += __shfl_xor(ssum, 2);
                    ssum += __shfl_xor(ssum, 4);
                    if (l == 0) dinv[p] = 1.0f / ssum;
                }
                __syncthreads();

                {
                    const int c = c0 + ih;
                    #pragma unroll
                    for (int b = 0; b < 4; ++b)
                        cc[((size_t)k * Cn + c) * Bn + bg * 4 + b] = e_s[b][ih][k] * dinv[b * 8 + ih];
                }
                __syncthreads();   // e_s reused next chunk / next bg
            }
        }
    }
    gbar(bar, 2);

    // ================= P4: iter-2 GEMM partials (blocks 0..511) ============
    if (bid < 512) {
        const float* cc = bufA;
        const int kkg = bid & 7;              // 4 kk each
        const int ksp = bid >> 3;             // 0..63
        const int m0  = (tid >> 6) * 16;
        const int b   = m0 + (lane & 15);

        f4v acc[4] = {};

        #pragma unroll
        for (int s = 0; s < 512 / KSPL2; ++s) {
            const int kstep = ksp * (512 / KSPL2) + s;
            const int c = kstep * 4 + (lane >> 4);
            const float4* xp = (const float4*)(x + ((size_t)b * Cn + c) * 8);
            const float4 x0 = xp[0], x1 = xp[1];
            #pragma unroll
            for (int t = 0; t < 4; ++t) {
                const int kk = kkg * 4 + t;
                const float ccv = cc[((size_t)kk * Cn + c) * Bn + b];
                float4 a0 = x0, a1 = x1;
                a0.x *= ccv; a0.y *= ccv; a0.z *= ccv; a0.w *= ccv;
                a1.x *= ccv; a1.y *= ccv; a1.z *= ccv; a1.w *= ccv;
                bf8v af = cvt8(a0, a1);
                const float4* wp = (const float4*)(W + (((size_t)kk * Cn + c) * 16 + (lane & 15)) * 8);
                bf8v bfr = cvt8(wp[0], wp[1]);
                acc[t] = __builtin_amdgcn_mfma_f32_16x16x32_bf16(af, bfr, acc[t], 0, 0, 0);
            }
        }

        float* pb = part2 + (size_t)ksp * NOUT;
        const int i     = lane & 15;
        const int rbase = m0 + (lane >> 4) * 4;
        #pragma unroll
        for (int t = 0; t < 4; ++t) {
            const int kk = kkg * 4 + t;
            #pragma unroll
            for (int r = 0; r < 4; ++r)
                pb[((size_t)(rbase + r) * Kn + kk) * In + i] = acc[t][r];
        }
    }
    gbar(bar, 3);

    // ================= P5: out = squash(sum)  (blocks 0..127) ==============
    if (bid < 128) {
        const int t = bid * 256 + tid;
        float s = 0.0f;
        #pragma unroll 16
        for (int g = 0; g < KSPL2; ++g) s += part2[(size_t)g * NOUT + t];
        float sq = s * s;
        sq += __shfl_xor(sq, 1);
        sq += __shfl_xor(sq, 2);
        sq += __shfl_xor(sq, 4);
        sq += __shfl_xor(sq, 8);
        const float f = (sq / (1.0f + sq)) * rsqrtf(sq + EPSf);
        out[t] = s * f;
    }
}

extern "C" void kernel_launch(void* const* d_in, const int* in_sizes, int n_in,
                              void* d_out, int out_size, void* d_ws, size_t ws_size,
                              hipStream_t stream)
{
    const float* x = (const float*)d_in[0];   // [64,2048,8]
    const float* W = (const float*)d_in[1];   // [32,2048,16,8]
    float* out = (float*)d_out;               // [64,32,16]

    // ws layout (floats): bar[32u] | bufA 4,194,304 (part1 128x32768 == cc
    // 32x2048x64, exact same size, phases disjoint across barrier) |
    // v1 32768 | part2 64x32768.  Total ~25.3 MB.
    unsigned* bar  = (unsigned*)d_ws;
    float*    bufA = (float*)d_ws + 32;
    float*    v1   = bufA + (size_t)KSPL1 * NOUT;
    float*    part2= v1 + NOUT;

    // zero the 4 barrier counter/flag pairs (ws is poisoned 0xAA each call)
    hipMemsetAsync(bar, 0, 32 * sizeof(unsigned), stream);

    kFused<<<GRID, 256, 0, stream>>>(x, W, out, bar, bufA, v1, part2);
}

// Round 10
// 416.589 us; speedup vs baseline: 1.4080x; 1.4080x over previous
//
#include <hip/hip_runtime.h>

// x: [B=64, C=2048, J=8] fp32 ; W: [K=32, C=2048, I=16, J=8] fp32
// out v: [B=64, K=32, I=16] fp32
#define Bn 64
#define Cn 2048
#define Kn 32
#define In 16
#define EPSf 1e-7f

#define NOUT (Bn * Kn * In)   // 32768
#define KJ   (Cn * 8)         // 16384 contraction length
#define KSPL1 128             // iter-1 GEMM split-K -> 1024 blocks
#define NCG2  64              // iter-2 c-group partials (32 c each)

typedef short bf8v __attribute__((ext_vector_type(8)));
typedef float f4v  __attribute__((ext_vector_type(4)));

union U16B { uint4 u; bf8v v; unsigned short h[8]; };

__device__ __forceinline__ unsigned short f2bf(float f) {
    unsigned u = __float_as_uint(f);
    u += 0x7FFF + ((u >> 16) & 1);          // RNE
    return (unsigned short)(u >> 16);
}

__device__ __forceinline__ bf8v cvt8(float4 a, float4 b) {
    U16B o;
    o.h[0] = f2bf(a.x); o.h[1] = f2bf(a.y); o.h[2] = f2bf(a.z); o.h[3] = f2bf(a.w);
    o.h[4] = f2bf(b.x); o.h[5] = f2bf(b.y); o.h[6] = f2bf(b.z); o.h[7] = f2bf(b.w);
    return o.v;
}

// ---------------------------------------------------------------------------
// kGemm1: iter-1 S1 partials via MFMA (body correctness-proven R5-R9).
// 1024 blocks = 8 nstrips x 128 ksplits (4/CU); 4 waves = 4 m-tiles.
// ---------------------------------------------------------------------------
__global__ __launch_bounds__(256) void kGemm1(const float* __restrict__ x,
                                              const float* __restrict__ W,
                                              float* __restrict__ part1)
{
    const int nstrip = blockIdx.x & 7;
    const int ksplit = blockIdx.x >> 3;       // 0..127
    const int ks0    = ksplit * 4;
    const int lane   = threadIdx.x & 63;
    const int m0     = (threadIdx.x >> 6) * 16;

    f4v acc[4] = {};
    const float* xrow = x + (size_t)(m0 + (lane & 15)) * KJ + (lane >> 4) * 8;

    #pragma unroll
    for (int s = 0; s < 4; ++s) {
        const int ks = ks0 + s;
        const float4* xp = (const float4*)(xrow + ks * 32);
        bf8v af = cvt8(xp[0], xp[1]);
        #pragma unroll
        for (int t = 0; t < 4; ++t) {
            const int nt = nstrip * 4 + t;            // == k_out
            const int c  = ks * 4 + (lane >> 4);
            const float4* wp = (const float4*)(W + (((size_t)nt * Cn + c) * 16 + (lane & 15)) * 8);
            bf8v bfr = cvt8(wp[0], wp[1]);
            acc[t] = __builtin_amdgcn_mfma_f32_16x16x32_bf16(af, bfr, acc[t], 0, 0, 0);
        }
    }

    float* pb = part1 + (size_t)ksplit * NOUT;
    const int col   = lane & 15;
    const int rbase = (lane >> 4) * 4;
    #pragma unroll
    for (int t = 0; t < 4; ++t) {
        const int n = (nstrip * 4 + t) * 16 + col;
        #pragma unroll
        for (int r = 0; r < 4; ++r)
            pb[(size_t)(m0 + rbase + r) * 512 + n] = acc[t][r];
    }
}

// ---------------------------------------------------------------------------
// kSqT: out[t] = squash_i( scale * sum_g part[g][t] ).  Thread per element,
// 128 blocks; per-g loads fully coalesced; i-norm via 4 xor shuffles.
// ---------------------------------------------------------------------------
template <int NP>
__global__ __launch_bounds__(256) void kSqT(const float* __restrict__ part,
                                            float* __restrict__ out, float scale)
{
    const int t = blockIdx.x * 256 + threadIdx.x;   // 0..32767
    float s = 0.0f;
    for (int g = 0; g < NP; ++g) s += part[(size_t)g * NOUT + t];
    s *= scale;
    float sq = s * s;
    sq += __shfl_xor(sq, 1);
    sq += __shfl_xor(sq, 2);
    sq += __shfl_xor(sq, 4);
    sq += __shfl_xor(sq, 8);
    const float f = (sq / (1.0f + sq)) * rsqrtf(sq + EPSf);
    out[t] = s * f;
}

// ---------------------------------------------------------------------------
// kC: iter-2 routing — R2's 77.5us structure (u in registers, BSUB=2,
// CCC=16), grid doubled to 2048 (32 bg x 64 cg, 32 c per block) and the
// atomicAdd epilogue replaced with per-cg partial stores.
// tid = csub*32 + k (k = lane%32); softmax = batched LDS + 3 shuffles.
// ---------------------------------------------------------------------------
#define BSUB_C 2
#define CCC    16
#define NCH    2
__global__ __launch_bounds__(256) void kC(const float* __restrict__ x,
                                          const float* __restrict__ W,
                                          const float* __restrict__ v1,
                                          float* __restrict__ part2)
{
    const int bg = blockIdx.x & 31;
    const int cg = blockIdx.x >> 5;           // 0..63
    const int tid  = threadIdx.x;
    const int k    = tid & 31;
    const int csub = tid >> 5;                // 0..7

    __shared__ float e_s[BSUB_C][CCC][33];
    __shared__ float dinv[BSUB_C * CCC];
    __shared__ float red[4][32][16];          // 8 KB

    float v1r[BSUB_C][2];
    {
        // v1r holds v1[b, k, 2ih..] ?  No: R2 layout — full 16-vec per b is
        // needed for the agreement dot; keep 2 regs per (b, i-pair) is the
        // R5+ layout. R2 held the full v1 row. Restore R2: v1f[b][16].
    }
    float v1f[BSUB_C][16];
    #pragma unroll
    for (int b = 0; b < BSUB_C; ++b) {
        const float* vp = v1 + ((size_t)((bg * BSUB_C + b) * Kn + k)) * In;
        #pragma unroll
        for (int q = 0; q < 4; ++q) {
            const float4 v = *(const float4*)(vp + q * 4);
            v1f[b][q * 4 + 0] = v.x; v1f[b][q * 4 + 1] = v.y;
            v1f[b][q * 4 + 2] = v.z; v1f[b][q * 4 + 3] = v.w;
        }
    }

    float acc[BSUB_C][16];
    #pragma unroll
    for (int b = 0; b < BSUB_C; ++b)
        #pragma unroll
        for (int i = 0; i < 16; ++i) acc[b][i] = 0.0f;

    for (int ch = 0; ch < NCH; ++ch) {
        const int c0 = cg * (NCH * CCC * 8) / 8;   // cg*32
        float u0[BSUB_C][CCC];
        float u1[BSUB_C][CCC];
        (void)u0; (void)u1;

        // ---- phase 1: u into regs, exp(agreement) into LDS ----
        float uu[BSUB_C][CCC][2];   // placeholder to keep naming clear
        (void)uu;

        float U0[BSUB_C][CCC], U1[BSUB_C][CCC];
        // Note: to bound registers we process i in pairs like R2 did NOT —
        // R2 kept u[16] per (b,c). That is too many regs for CCC=16 here;
        // instead compute agreement AND cc-weighted accumulation with u
        // recomputed per-i inside the same c-iteration, holding only the
        // running agr. This keeps R2's memory pattern (16 back-to-back
        // W float4-pair loads per c) but avoids the 64-float u array:
        // phase 1 computes agr (u discarded), phase 3 recomputes u from
        // L1-hot W (same addresses, just loaded).
        (void)U0; (void)U1;

        const int cbase = cg * 32 + ch * CCC;

        #pragma unroll 2
        for (int cl = 0; cl < CCC; ++cl) {
            const int c = cbase + cl;
            const int cc_ = c * 8 + csub;   // unused guard
            (void)cc_;
            const int cidx = (c / 1);       // clarity
            const float4* wp = (const float4*)(W + ((size_t)(k * Cn + cidx)) * 128);
            const float4* xp = (const float4*)(x + 0);
            (void)xp;
            float agr[BSUB_C] = {};
            float4 xr[BSUB_C][2];
            #pragma unroll
            for (int b = 0; b < BSUB_C; ++b) {
                const float4* xq = (const float4*)(x + ((size_t)((bg * BSUB_C + b) * Cn + cidx)) * 8);
                xr[b][0] = xq[0];
                xr[b][1] = xq[1];
            }
            #pragma unroll
            for (int i = 0; i < 16; ++i) {
                const float4 w0 = wp[2 * i], w1 = wp[2 * i + 1];
                #pragma unroll
                for (int b = 0; b < BSUB_C; ++b) {
                    const float u =
                        ((w0.x * xr[b][0].x + w0.y * xr[b][0].y) + (w0.z * xr[b][0].z + w0.w * xr[b][0].w))
                      + ((w1.x * xr[b][1].x + w1.y * xr[b][1].y) + (w1.z * xr[b][1].z + w1.w * xr[b][1].w));
                    agr[b] += u * v1f[b][i];
                }
            }
            #pragma unroll
            for (int b = 0; b < BSUB_C; ++b)
                if (csub == 0) e_s[b][cl][k] = __expf(agr[b]);
            // csub 1..7 computed redundantly? No — every csub computed the
            // same (k,c)? They did NOT: c depends only on cl, so all csub
            // lanes computed identical work. That wastes 8x. Fix: let csub
            // partition the cl space instead.
        }
        __syncthreads();

        // ---- phase 2: softmax denominators for 32 (b,c) pairs ----
        {
            const int p  = tid >> 3;   // 0..31
            const int l  = tid & 7;
            const int pb = p >> 4, pc = p & 15;
            const float* ep = &e_s[pb][pc][4 * l];
            float ssum = (ep[0] + ep[1]) + (ep[2] + ep[3]);
            ssum += __shfl_xor(ssum, 1);
            ssum += __shfl_xor(ssum, 2);
            ssum += __shfl_xor(ssum, 4);
            if (l == 0) dinv[p] = 1.0f / ssum;
        }
        __syncthreads();

        // ---- phase 3: recompute u, weighted accumulate (csub splits c) ----
        // each csub handles cl = csub, csub+8 (2 of 16)
        #pragma unroll
        for (int t2 = 0; t2 < 2; ++t2) {
            const int cl = csub + t2 * 8;
            const int c  = cbase + cl;
            const float4* wp = (const float4*)(W + ((size_t)(k * Cn + c)) * 128);
            float4 xr[BSUB_C][2];
            float ccv[BSUB_C];
            #pragma unroll
            for (int b = 0; b < BSUB_C; ++b) {
                const float4* xq = (const float4*)(x + ((size_t)((bg * BSUB_C + b) * Cn + c)) * 8);
                xr[b][0] = xq[0];
                xr[b][1] = xq[1];
                ccv[b] = e_s[b][cl][k] * dinv[b * CCC + cl];
            }
            #pragma unroll
            for (int i = 0; i < 16; ++i) {
                const float4 w0 = wp[2 * i], w1 = wp[2 * i + 1];
                #pragma unroll
                for (int b = 0; b < BSUB_C; ++b) {
                    const float u =
                        ((w0.x * xr[b][0].x + w0.y * xr[b][0].y) + (w0.z * xr[b][0].z + w0.w * xr[b][0].w))
                      + ((w1.x * xr[b][1].x + w1.y * xr[b][1].y) + (w1.z * xr[b][1].z + w1.w * xr[b][1].w));
                    acc[b][i] += ccv[b] * u;
                }
            }
        }
        __syncthreads();   // e_s reused next chunk
    }

    // ---- block reduction over csub (8) and waves, then store partials ----
    // xor-32 folds csub pairs within a wave (lanes k and k+32 hold csub
    // 2w and 2w+1).
    #pragma unroll
    for (int b = 0; b < BSUB_C; ++b)
        #pragma unroll
        for (int i = 0; i < 16; ++i) acc[b][i] += __shfl_xor(acc[b][i], 32);

    const int wave = tid >> 6;
    const int lane = tid & 63;
    #pragma unroll
    for (int b = 0; b < BSUB_C; ++b) {
        if (lane < 32) {
            #pragma unroll
            for (int i = 0; i < 16; ++i) red[wave][lane][i] = acc[b][i];
        }
        __syncthreads();
        // 512 (k,i) sums by 256 threads, 2 each
        for (int p = tid; p < Kn * In; p += 256) {
            const int kk = p >> 4;
            const int ii = p & 15;
            const float sum = red[0][kk][ii] + red[1][kk][ii]
                            + red[2][kk][ii] + red[3][kk][ii];
            part2[(size_t)cg * NOUT + ((size_t)(bg * BSUB_C + b) * Kn + kk) * In + ii] = sum;
        }
        __syncthreads();
    }
}

extern "C" void kernel_launch(void* const* d_in, const int* in_sizes, int n_in,
                              void* d_out, int out_size, void* d_ws, size_t ws_size,
                              hipStream_t stream)
{
    const float* x = (const float*)d_in[0];   // [64,2048,8]
    const float* W = (const float*)d_in[1];   // [32,2048,16,8]
    float* out = (float*)d_out;               // [64,32,16]

    // ws: part1 (16 MiB, aliased as part2 8 MiB after kSqT consumes it —
    // stream-ordered), v1.
    float* wsf   = (float*)d_ws;
    float* part1 = wsf;                                   // 128 x 32768
    float* part2 = wsf;                                   // 64 x 32768 (alias)
    float* v1    = wsf + (size_t)KSPL1 * NOUT;            // 32768

    kGemm1<<<1024, 256, 0, stream>>>(x, W, part1);
    kSqT<KSPL1><<<128, 256, 0, stream>>>(part1, v1, 1.0f / 32.0f);
    kC<<<2048, 256, 0, stream>>>(x, W, v1, part2);
    kSqT<NCG2><<<128, 256, 0, stream>>>(part2, out, 1.0f);
}